// Round 3
// baseline (1840.578 us; speedup 1.0000x reference)
//
#include <hip/hip_runtime.h>
#include <math.h>

#define EF 128
#define NPTS 32768
#define KNN 8
#define MVOX 8192
#define GDIM 32
#define NVOXG (GDIM*GDIM*GDIM)

typedef __attribute__((ext_vector_type(8))) short bfrag;   // 8 x bf16
typedef __attribute__((ext_vector_type(4))) float f32x4;

__device__ __forceinline__ float lrelu(float x) { return x > 0.f ? x : 0.01f * x; }
__device__ __forceinline__ short f2b(float f) {            // fp32 -> bf16 (RNE)
    unsigned u = __float_as_uint(f);
    return (short)((u + 0x7fff + ((u >> 16) & 1)) >> 16);
}
#define MFMA(a,b,c) __builtin_amdgcn_mfma_f32_16x16x32_bf16((a),(b),(c),0,0,0)

// ---------------- weight packing: W[k][col] (strided) -> [step][ct][lane][8] bf16 ----------------
__global__ void k_pack_w(const float* __restrict__ src, short* __restrict__ dst,
                         int K_real, int n_steps, int k_str, int c_str) {
    int t = blockIdx.x * 256 + threadIdx.x;
    int total = n_steps * 4096;
    if (t >= total) return;
    int r = t & 7, l = (t >> 3) & 63, ct = (t >> 9) & 7, s = t >> 12;
    int k = s * 32 + (l >> 4) * 8 + r;
    int col = ct * 16 + (l & 15);
    float v = (k < K_real) ? src[(size_t)k * k_str + (size_t)col * c_str] : 0.f;
    dst[t] = f2b(v);
}
// conv3x3x3 weights [o][ci][27] -> [tap*4+cc][ct][lane][8]
__global__ void k_pack_wc1(const float* __restrict__ src, short* __restrict__ dst) {
    int t = blockIdx.x * 256 + threadIdx.x;
    if (t >= 108 * 4096) return;
    int r = t & 7, l = (t >> 3) & 63, ct = (t >> 9) & 7, s = t >> 12;
    int tap = s >> 2;
    int ci = (s & 3) * 32 + (l >> 4) * 8 + r;
    int col = ct * 16 + (l & 15);
    dst[t] = f2b(src[((size_t)col * 128 + ci) * 27 + tap]);
}

// ---------------- pc_conv_first: M=64 rows/wave ----------------
__global__ __launch_bounds__(256) void k_pcfirst(
    const float* __restrict__ xyz, const float* __restrict__ W1, const float* __restrict__ b1,
    const short* __restrict__ w2p, const float* __restrict__ b2,
    float* __restrict__ out32, short* __restrict__ out16) {
    __shared__ __align__(16) char t_raw[4][16384];
    int wid = threadIdx.x >> 6, lane = threadIdx.x & 63, lrow = lane & 15, lq = lane >> 4;
    int rowbase = (blockIdx.x * 4 + wid) * 64;
    char* tb = t_raw[wid];
    // 3->128 on VALU: lane handles one row
    {
        int grow = rowbase + lane;
        float x0 = xyz[grow * 3], y0 = xyz[grow * 3 + 1], z0 = xyz[grow * 3 + 2];
        int rowoff = lane * 256, rxor = (lane & 7) << 4;
        #pragma unroll
        for (int j0 = 0; j0 < 128; j0 += 8) {
            bfrag v;
            #pragma unroll
            for (int j = 0; j < 8; ++j) {
                int col = j0 + j;
                v[j] = f2b(lrelu(b1[col] + x0 * W1[col] + y0 * W1[128 + col] + z0 * W1[256 + col]));
            }
            *(bfrag*)(tb + rowoff + ((j0 * 2) ^ rxor)) = v;
        }
    }
    __syncthreads();
    float bb2[8];
    #pragma unroll
    for (int ct = 0; ct < 8; ++ct) bb2[ct] = b2[ct * 16 + lrow];
    f32x4 zv = {0.f, 0.f, 0.f, 0.f};
    f32x4 acc[4][8];
    #pragma unroll
    for (int rt = 0; rt < 4; ++rt)
        #pragma unroll
        for (int ct = 0; ct < 8; ++ct) acc[rt][ct] = zv;
    const bfrag* bp2 = (const bfrag*)w2p;
    #pragma unroll
    for (int s = 0; s < 4; ++s) {
        bfrag av[4];
        #pragma unroll
        for (int rt = 0; rt < 4; ++rt)
            av[rt] = *(const bfrag*)(tb + (rt * 16 + lrow) * 256 + (((s * 32 + lq * 8) * 2) ^ ((lrow & 7) << 4)));
        #pragma unroll
        for (int ct = 0; ct < 8; ++ct) {
            bfrag B = bp2[(s * 8 + ct) * 64 + lane];
            #pragma unroll
            for (int rt = 0; rt < 4; ++rt) acc[rt][ct] = MFMA(av[rt], B, acc[rt][ct]);
        }
    }
    #pragma unroll
    for (int rt = 0; rt < 4; ++rt)
        #pragma unroll
        for (int ct = 0; ct < 8; ++ct) {
            float m = -INFINITY;
            #pragma unroll
            for (int r = 0; r < 4; ++r) m = fmaxf(m, acc[rt][ct][r] + bb2[ct]);
            m = fmaxf(m, __shfl_xor(m, 16, 64));
            if ((lq & 1) == 0) {
                int p = (rowbase >> 3) + rt * 2 + (lq >> 1);
                float v = lrelu(m);
                out32[(size_t)p * 128 + ct * 16 + lrow] = v;
                out16[(size_t)p * 128 + ct * 16 + lrow] = f2b(v);
            }
        }
}

// ---------------- pc_conv: M=64 rows/wave, gather + 131->128 + 128->128 + maxpool ----------------
__global__ __launch_bounds__(256) void k_pcconv(
    const short* __restrict__ fin16, const int* __restrict__ idx, const float* __restrict__ xyz,
    const short* __restrict__ w1p, const float* __restrict__ b1,
    const short* __restrict__ w2p, const float* __restrict__ b2,
    float* __restrict__ out32, short* __restrict__ out16) {
    __shared__ __align__(16) char t_raw[4][16384];
    int wid = threadIdx.x >> 6, lane = threadIdx.x & 63, lrow = lane & 15, lq = lane >> 4;
    int rowbase = (blockIdx.x * 4 + wid) * 64;
    char* tb = t_raw[wid];
    int nb[4];
    #pragma unroll
    for (int rt = 0; rt < 4; ++rt) nb[rt] = idx[rowbase + rt * 16 + lrow];
    float bb1[8], bb2[8];
    #pragma unroll
    for (int ct = 0; ct < 8; ++ct) { bb1[ct] = b1[ct * 16 + lrow]; bb2[ct] = b2[ct * 16 + lrow]; }
    f32x4 zv = {0.f, 0.f, 0.f, 0.f};
    f32x4 acc[4][8];
    #pragma unroll
    for (int rt = 0; rt < 4; ++rt)
        #pragma unroll
        for (int ct = 0; ct < 8; ++ct) acc[rt][ct] = zv;
    const bfrag* bp1 = (const bfrag*)w1p;
    #pragma unroll
    for (int s = 0; s < 4; ++s) {
        bfrag a[4];
        #pragma unroll
        for (int rt = 0; rt < 4; ++rt)
            a[rt] = *((const bfrag*)(fin16 + (size_t)nb[rt] * 128) + s * 4 + lq);
        #pragma unroll
        for (int ct = 0; ct < 8; ++ct) {
            bfrag B = bp1[(s * 8 + ct) * 64 + lane];
            #pragma unroll
            for (int rt = 0; rt < 4; ++rt) acc[rt][ct] = MFMA(a[rt], B, acc[rt][ct]);
        }
    }
    {   // k-step 4: xyz concat (cols 128..130)
        bfrag a4[4];
        #pragma unroll
        for (int rt = 0; rt < 4; ++rt) {
            #pragma unroll
            for (int r = 0; r < 8; ++r) a4[rt][r] = 0;
            if (lq == 0) {
                int gr = rowbase + rt * 16 + lrow;
                a4[rt][0] = f2b(xyz[gr * 3]); a4[rt][1] = f2b(xyz[gr * 3 + 1]); a4[rt][2] = f2b(xyz[gr * 3 + 2]);
            }
        }
        #pragma unroll
        for (int ct = 0; ct < 8; ++ct) {
            bfrag B = bp1[(4 * 8 + ct) * 64 + lane];
            #pragma unroll
            for (int rt = 0; rt < 4; ++rt) acc[rt][ct] = MFMA(a4[rt], B, acc[rt][ct]);
        }
    }
    #pragma unroll
    for (int rt = 0; rt < 4; ++rt)
        #pragma unroll
        for (int ct = 0; ct < 8; ++ct)
            #pragma unroll
            for (int r = 0; r < 4; ++r) {
                int row = rt * 16 + lq * 4 + r, col = ct * 16 + lrow;
                *(short*)(tb + row * 256 + ((col * 2) ^ ((row & 7) << 4))) = f2b(lrelu(acc[rt][ct][r] + bb1[ct]));
            }
    __syncthreads();
    f32x4 acc2[4][8];
    #pragma unroll
    for (int rt = 0; rt < 4; ++rt)
        #pragma unroll
        for (int ct = 0; ct < 8; ++ct) acc2[rt][ct] = zv;
    const bfrag* bp2 = (const bfrag*)w2p;
    #pragma unroll
    for (int s = 0; s < 4; ++s) {
        bfrag av[4];
        #pragma unroll
        for (int rt = 0; rt < 4; ++rt)
            av[rt] = *(const bfrag*)(tb + (rt * 16 + lrow) * 256 + (((s * 32 + lq * 8) * 2) ^ ((lrow & 7) << 4)));
        #pragma unroll
        for (int ct = 0; ct < 8; ++ct) {
            bfrag B = bp2[(s * 8 + ct) * 64 + lane];
            #pragma unroll
            for (int rt = 0; rt < 4; ++rt) acc2[rt][ct] = MFMA(av[rt], B, acc2[rt][ct]);
        }
    }
    #pragma unroll
    for (int rt = 0; rt < 4; ++rt)
        #pragma unroll
        for (int ct = 0; ct < 8; ++ct) {
            float m = -INFINITY;
            #pragma unroll
            for (int r = 0; r < 4; ++r) m = fmaxf(m, acc2[rt][ct][r] + bb2[ct]);
            m = fmaxf(m, __shfl_xor(m, 16, 64));
            if ((lq & 1) == 0) {
                int p = (rowbase >> 3) + rt * 2 + (lq >> 1);
                float v = lrelu(m);
                out32[(size_t)p * 128 + ct * 16 + lrow] = v;
                out16[(size_t)p * 128 + ct * 16 + lrow] = f2b(v);
            }
        }
}

// ---------------- pc_res: M=64 rows/wave ----------------
__global__ __launch_bounds__(256) void k_pcres(
    const float* __restrict__ fin32, const short* __restrict__ fin16,
    const short* __restrict__ w1p, const float* __restrict__ b1,
    const short* __restrict__ w2p, const float* __restrict__ b2,
    float* __restrict__ out32, short* __restrict__ out16) {
    __shared__ __align__(16) char t_raw[4][16384];
    int wid = threadIdx.x >> 6, lane = threadIdx.x & 63, lrow = lane & 15, lq = lane >> 4;
    int rowbase = (blockIdx.x * 4 + wid) * 64;
    char* tb = t_raw[wid];
    float bb1[8], bb2[8];
    #pragma unroll
    for (int ct = 0; ct < 8; ++ct) { bb1[ct] = b1[ct * 16 + lrow]; bb2[ct] = b2[ct * 16 + lrow]; }
    f32x4 zv = {0.f, 0.f, 0.f, 0.f};
    f32x4 acc[4][8];
    #pragma unroll
    for (int rt = 0; rt < 4; ++rt)
        #pragma unroll
        for (int ct = 0; ct < 8; ++ct) acc[rt][ct] = zv;
    const bfrag* bp1 = (const bfrag*)w1p;
    #pragma unroll
    for (int s = 0; s < 4; ++s) {
        bfrag a[4];
        #pragma unroll
        for (int rt = 0; rt < 4; ++rt)
            a[rt] = *((const bfrag*)(fin16 + (size_t)(rowbase + rt * 16 + lrow) * 128) + s * 4 + lq);
        #pragma unroll
        for (int ct = 0; ct < 8; ++ct) {
            bfrag B = bp1[(s * 8 + ct) * 64 + lane];
            #pragma unroll
            for (int rt = 0; rt < 4; ++rt) acc[rt][ct] = MFMA(a[rt], B, acc[rt][ct]);
        }
    }
    #pragma unroll
    for (int rt = 0; rt < 4; ++rt)
        #pragma unroll
        for (int ct = 0; ct < 8; ++ct)
            #pragma unroll
            for (int r = 0; r < 4; ++r) {
                int row = rt * 16 + lq * 4 + r, col = ct * 16 + lrow;
                *(short*)(tb + row * 256 + ((col * 2) ^ ((row & 7) << 4))) = f2b(lrelu(acc[rt][ct][r] + bb1[ct]));
            }
    __syncthreads();
    f32x4 acc2[4][8];
    #pragma unroll
    for (int rt = 0; rt < 4; ++rt)
        #pragma unroll
        for (int ct = 0; ct < 8; ++ct) acc2[rt][ct] = zv;
    const bfrag* bp2 = (const bfrag*)w2p;
    #pragma unroll
    for (int s = 0; s < 4; ++s) {
        bfrag av[4];
        #pragma unroll
        for (int rt = 0; rt < 4; ++rt)
            av[rt] = *(const bfrag*)(tb + (rt * 16 + lrow) * 256 + (((s * 32 + lq * 8) * 2) ^ ((lrow & 7) << 4)));
        #pragma unroll
        for (int ct = 0; ct < 8; ++ct) {
            bfrag B = bp2[(s * 8 + ct) * 64 + lane];
            #pragma unroll
            for (int rt = 0; rt < 4; ++rt) acc2[rt][ct] = MFMA(av[rt], B, acc2[rt][ct]);
        }
    }
    #pragma unroll
    for (int rt = 0; rt < 4; ++rt)
        #pragma unroll
        for (int ct = 0; ct < 8; ++ct)
            #pragma unroll
            for (int r = 0; r < 4; ++r) {
                int row = rt * 16 + lq * 4 + r, col = ct * 16 + lrow;
                size_t o = (size_t)(rowbase + row) * 128 + col;
                float v = lrelu(acc2[rt][ct][r] + bb2[ct] + fin32[o]);
                out32[o] = v; out16[o] = f2b(v);
            }
}

// ---------------- conv3d 3x3x3 implicit GEMM, wave = M=128 voxels x N=32 ch, fused 1x1+res ----------------
__global__ __launch_bounds__(256) void k_conv3(
    const float* __restrict__ gin32, const short* __restrict__ gin16,
    const short* __restrict__ w1p, const float* __restrict__ b1,
    const short* __restrict__ w2p, const float* __restrict__ b2,
    float* __restrict__ gout32, short* __restrict__ gout16) {
    __shared__ __align__(16) char tb[32768];
    int wid = threadIdx.x >> 6, lane = threadIdx.x & 63, lrow = lane & 15, lq = lane >> 4;
    int va = blockIdx.x >> 3, vb0 = (blockIdx.x & 7) * 4;
    int ctg0 = wid * 2;
    float bb1[2], bb2[2];
    #pragma unroll
    for (int ct = 0; ct < 2; ++ct) {
        bb1[ct] = b1[(ctg0 + ct) * 16 + lrow];
        bb2[ct] = b2[(ctg0 + ct) * 16 + lrow];
    }
    f32x4 zv = {0.f, 0.f, 0.f, 0.f};
    f32x4 acc[8][2];
    #pragma unroll
    for (int rt = 0; rt < 8; ++rt) { acc[rt][0] = zv; acc[rt][1] = zv; }
    bfrag zf;
    #pragma unroll
    for (int r = 0; r < 8; ++r) zf[r] = 0;
    const bfrag* bp1 = (const bfrag*)w1p;
    for (int da = -1; da <= 1; ++da) {
        int aa = va + da;
        bool oka = (unsigned)aa < 32u;
        for (int db = -1; db <= 1; ++db) {
            #pragma unroll 1
            for (int dc = -1; dc <= 1; ++dc) {
                int tap = (da + 1) * 9 + (db + 1) * 3 + (dc + 1);
                int aoff[8]; bool okr[8];
                #pragma unroll
                for (int rt = 0; rt < 8; ++rt) {
                    int l = rt >> 1, vbl = vb0 + l + db;
                    int vc = ((rt & 1) << 4) + lrow + dc;
                    bool ok = oka && ((unsigned)vbl < 32u) && ((unsigned)vc < 32u);
                    aoff[rt] = ok ? ((aa * 32 + vbl) * 32 + vc) * 128 : 0;
                    okr[rt] = ok;
                }
                #pragma unroll
                for (int s = 0; s < 4; ++s) {
                    bfrag a[8];
                    #pragma unroll
                    for (int rt = 0; rt < 8; ++rt) {
                        bfrag t = *((const bfrag*)(gin16 + aoff[rt]) + s * 4 + lq);
                        a[rt] = okr[rt] ? t : zf;
                    }
                    #pragma unroll
                    for (int ct = 0; ct < 2; ++ct) {
                        bfrag B = bp1[((tap * 4 + s) * 8 + ctg0 + ct) * 64 + lane];
                        #pragma unroll
                        for (int rt = 0; rt < 8; ++rt) acc[rt][ct] = MFMA(a[rt], B, acc[rt][ct]);
                    }
                }
            }
        }
    }
    #pragma unroll
    for (int rt = 0; rt < 8; ++rt)
        #pragma unroll
        for (int ct = 0; ct < 2; ++ct)
            #pragma unroll
            for (int r = 0; r < 4; ++r) {
                int row = rt * 16 + lq * 4 + r, col = (ctg0 + ct) * 16 + lrow;
                *(short*)(tb + row * 256 + ((col * 2) ^ ((row & 7) << 4))) = f2b(lrelu(acc[rt][ct][r] + bb1[ct]));
            }
    __syncthreads();
    f32x4 acc2[8][2];
    #pragma unroll
    for (int rt = 0; rt < 8; ++rt) { acc2[rt][0] = zv; acc2[rt][1] = zv; }
    const bfrag* bp2 = (const bfrag*)w2p;
    #pragma unroll
    for (int s = 0; s < 4; ++s) {
        bfrag av[8];
        #pragma unroll
        for (int rt = 0; rt < 8; ++rt)
            av[rt] = *(const bfrag*)(tb + (rt * 16 + lrow) * 256 + (((s * 32 + lq * 8) * 2) ^ ((lrow & 7) << 4)));
        #pragma unroll
        for (int ct = 0; ct < 2; ++ct) {
            bfrag B = bp2[(s * 8 + ctg0 + ct) * 64 + lane];
            #pragma unroll
            for (int rt = 0; rt < 8; ++rt) acc2[rt][ct] = MFMA(av[rt], B, acc2[rt][ct]);
        }
    }
    size_t base = (size_t)(va * 1024 + vb0 * 32) * 128;
    #pragma unroll
    for (int rt = 0; rt < 8; ++rt)
        #pragma unroll
        for (int ct = 0; ct < 2; ++ct)
            #pragma unroll
            for (int r = 0; r < 4; ++r) {
                int row = rt * 16 + lq * 4 + r;
                size_t o = base + (size_t)row * 128 + (ctg0 + ct) * 16 + lrow;
                float v = lrelu(acc2[rt][ct][r] + bb2[ct] + gin32[o]);
                gout32[o] = v; gout16[o] = f2b(v);
            }
}

// ---------------- small kernels ----------------
__global__ void k_vmin(const int* __restrict__ vx, int M, int* __restrict__ vmin) {
    __shared__ int sm[3 * 256];
    int t = threadIdx.x;
    int m0 = 0x7fffffff, m1 = 0x7fffffff, m2 = 0x7fffffff;
    for (int i = t; i < M; i += 256) {
        m0 = min(m0, vx[i * 3 + 0]); m1 = min(m1, vx[i * 3 + 1]); m2 = min(m2, vx[i * 3 + 2]);
    }
    sm[t] = m0; sm[256 + t] = m1; sm[512 + t] = m2;
    __syncthreads();
    for (int s = 128; s > 0; s >>= 1) {
        if (t < s) {
            sm[t] = min(sm[t], sm[t + s]);
            sm[256 + t] = min(sm[256 + t], sm[256 + t + s]);
            sm[512 + t] = min(sm[512 + t], sm[512 + t + s]);
        }
        __syncthreads();
    }
    if (t == 0) { vmin[0] = sm[0]; vmin[1] = sm[256]; vmin[2] = sm[512]; }
}

__global__ void k_scatter(const float* __restrict__ vf, const int* __restrict__ vx,
                          const int* __restrict__ vmin, float* __restrict__ g32, short* __restrict__ g16) {
    int m = blockIdx.x, j = threadIdx.x;
    int v0 = vx[m * 3 + 0] - vmin[0];
    int v1 = vx[m * 3 + 1] - vmin[1];
    int v2 = vx[m * 3 + 2] - vmin[2];
    size_t o = (size_t)(((v0 * GDIM) + v1) * GDIM + v2) * EF + j;
    float v = vf[(size_t)m * EF + j];
    g32[o] = v; g16[o] = f2b(v);
}

__global__ void k_final(const float* __restrict__ grid, const int* __restrict__ vx,
                        const int* __restrict__ vmin,
                        const float* __restrict__ W1, const float* __restrict__ b1,
                        const float* __restrict__ W2, const float* __restrict__ b2,
                        const float* __restrict__ W3, const float* __restrict__ b3,
                        float* __restrict__ out) {
    __shared__ float xs[EF], t[EF];
    int m = blockIdx.x, j = threadIdx.x;
    int v0 = vx[m * 3 + 0] - vmin[0];
    int v1 = vx[m * 3 + 1] - vmin[1];
    int v2 = vx[m * 3 + 2] - vmin[2];
    xs[j] = grid[(size_t)(((v0 * GDIM) + v1) * GDIM + v2) * EF + j];
    __syncthreads();
    float s = b1[j];
    #pragma unroll 4
    for (int c = 0; c < EF; ++c) s += xs[c] * W1[c * EF + j];
    t[j] = lrelu(s);
    __syncthreads();
    float s2 = b2[j];
    #pragma unroll 4
    for (int c = 0; c < EF; ++c) s2 += t[c] * W2[c * EF + j];
    __syncthreads();
    xs[j] = lrelu(s2);
    __syncthreads();
    if (j < 3) {
        float o = b3[j];
        for (int c = 0; c < EF; ++c) o += xs[c] * W3[c * 3 + j];
        out[(size_t)m * 3 + j] = 1.f / (1.f + expf(-o));
    }
}

extern "C" void kernel_launch(void* const* d_in, const int* in_sizes, int n_in,
                              void* d_out, int out_size, void* d_ws, size_t ws_size,
                              hipStream_t stream) {
    const int*   pc_idx  = (const int*)  d_in[0];
    const float* pc_xyz  = (const float*)d_in[1];
    const int*   vox_int = (const int*)  d_in[2];
    const int*   vox_idx = (const int*)  d_in[3];
    const float* vox_xyz = (const float*)d_in[4];
    const float* pcf_W1  = (const float*)d_in[5];
    const float* pcf_b1  = (const float*)d_in[6];
    const float* pcf_W2  = (const float*)d_in[7];
    const float* pcf_b2  = (const float*)d_in[8];
    const float* pcres_W1 = (const float*)d_in[9];
    const float* pcres_b1 = (const float*)d_in[10];
    const float* pcres_W2 = (const float*)d_in[11];
    const float* pcres_b2 = (const float*)d_in[12];
    const float* pcc_W1  = (const float*)d_in[13];
    const float* pcc_b1  = (const float*)d_in[14];
    const float* pcc_W2  = (const float*)d_in[15];
    const float* pcc_b2  = (const float*)d_in[16];
    const float* r3_Wc1  = (const float*)d_in[17];
    const float* r3_bc1  = (const float*)d_in[18];
    const float* r3_Wc2  = (const float*)d_in[19];
    const float* r3_bc2  = (const float*)d_in[20];
    const float* lin1_W  = (const float*)d_in[21];
    const float* lin1_b  = (const float*)d_in[22];
    const float* lin2_W  = (const float*)d_in[23];
    const float* lin2_b  = (const float*)d_in[24];
    const float* linb_W  = (const float*)d_in[25];
    const float* linb_b  = (const float*)d_in[26];

    const size_t NE = (size_t)NPTS * EF;   // 4M elements
    float* A32 = (float*)d_ws;
    float* B32 = A32 + NE;
    short* A16 = (short*)(B32 + NE);
    short* B16 = A16 + NE;
    float* Y32 = (float*)(B16 + NE);
    short* Y16 = (short*)(Y32 + NE);
    short* pcf_w2p = Y16 + NE;
    short* pcc_w1p = pcf_w2p + 4 * 4096;       // 6 layers x 5 steps
    short* pcc_w2p = pcc_w1p + 6 * 5 * 4096;   // 6 x 4
    short* pcr_w1p = pcc_w2p + 6 * 4 * 4096;   // 7 x 4
    short* pcr_w2p = pcr_w1p + 7 * 4 * 4096;
    short* wc2p    = pcr_w2p + 7 * 4 * 4096;   // 8 x 4
    short* wc1p    = wc2p    + 8 * 4 * 4096;   // 108 steps (one layer at a time)
    int*   vmin    = (int*)(wc1p + 108 * 4096);

    // ---- pack weights ----
    k_pack_w<<<64, 256, 0, stream>>>(pcf_W2, pcf_w2p, 128, 4, 128, 1);
    for (int i = 0; i < 6; ++i) {
        k_pack_w<<<80, 256, 0, stream>>>(pcc_W1 + (size_t)i * 131 * 128, pcc_w1p + (size_t)i * 5 * 4096, 131, 5, 128, 1);
        k_pack_w<<<64, 256, 0, stream>>>(pcc_W2 + (size_t)i * 128 * 128, pcc_w2p + (size_t)i * 4 * 4096, 128, 4, 128, 1);
    }
    for (int i = 0; i < 7; ++i) {
        k_pack_w<<<64, 256, 0, stream>>>(pcres_W1 + (size_t)i * 128 * 128, pcr_w1p + (size_t)i * 4 * 4096, 128, 4, 128, 1);
        k_pack_w<<<64, 256, 0, stream>>>(pcres_W2 + (size_t)i * 128 * 128, pcr_w2p + (size_t)i * 4 * 4096, 128, 4, 128, 1);
    }
    for (int i = 0; i < 8; ++i)
        k_pack_w<<<64, 256, 0, stream>>>(r3_Wc2 + (size_t)i * 128 * 128, wc2p + (size_t)i * 4 * 4096, 128, 4, 1, 128);

    // ---- point-cloud stack (A/B ping-pong; fp32 master + bf16 mirror) ----
    k_pcfirst<<<NPTS * KNN / 256, 256, 0, stream>>>(pc_xyz, pcf_W1, pcf_b1, pcf_w2p, pcf_b2, A32, A16);
    k_pcres<<<NPTS / 256, 256, 0, stream>>>(A32, A16, pcr_w1p, pcres_b1, pcr_w2p, pcres_b2, B32, B16);
    for (int i = 0; i < 5; ++i) {
        k_pcconv<<<NPTS * KNN / 256, 256, 0, stream>>>(B16, pc_idx, pc_xyz,
            pcc_w1p + (size_t)i * 5 * 4096, pcc_b1 + i * EF,
            pcc_w2p + (size_t)i * 4 * 4096, pcc_b2 + i * EF, A32, A16);
        k_pcres<<<NPTS / 256, 256, 0, stream>>>(A32, A16,
            pcr_w1p + (size_t)(i + 1) * 4 * 4096, pcres_b1 + (i + 1) * EF,
            pcr_w2p + (size_t)(i + 1) * 4 * 4096, pcres_b2 + (i + 1) * EF, B32, B16);
    }
    k_pcconv<<<MVOX * KNN / 256, 256, 0, stream>>>(B16, vox_idx, vox_xyz,
        pcc_w1p + (size_t)5 * 5 * 4096, pcc_b1 + 5 * EF,
        pcc_w2p + (size_t)5 * 4 * 4096, pcc_b2 + 5 * EF, A32, A16);
    k_pcres<<<MVOX / 256, 256, 0, stream>>>(A32, A16,
        pcr_w1p + (size_t)6 * 4 * 4096, pcres_b1 + 6 * EF,
        pcr_w2p + (size_t)6 * 4 * 4096, pcres_b2 + 6 * EF, B32, B16);
    // voxfeat now in B32 (rows 0..MVOX-1); A buffers are dead -> reuse as grid X

    k_vmin<<<1, 256, 0, stream>>>(vox_int, MVOX, vmin);
    hipMemsetAsync(A32, 0, NE * sizeof(float), stream);
    hipMemsetAsync(A16, 0, NE * sizeof(short), stream);
    k_scatter<<<MVOX, 128, 0, stream>>>(B32, vox_int, vmin, A32, A16);

    // ---- 8 x resnet_block_rec3 (ping-pong A <-> Y) ----
    float* cur32 = A32; short* cur16 = A16;
    float* nxt32 = Y32; short* nxt16 = Y16;
    for (int i = 0; i < 8; ++i) {
        k_pack_wc1<<<1728, 256, 0, stream>>>(r3_Wc1 + (size_t)i * 128 * 128 * 27, wc1p);
        k_conv3<<<256, 256, 0, stream>>>(cur32, cur16, wc1p, r3_bc1 + i * EF,
                                         wc2p + (size_t)i * 4 * 4096, r3_bc2 + i * EF,
                                         nxt32, nxt16);
        float* t32 = cur32; cur32 = nxt32; nxt32 = t32;
        short* t16 = cur16; cur16 = nxt16; nxt16 = t16;
    }

    // ---- head ----
    k_final<<<MVOX, 128, 0, stream>>>(cur32, vox_int, vmin,
                                      lin1_W, lin1_b, lin2_W, lin2_b, linb_W, linb_b,
                                      (float*)d_out);
}